// Round 4
// baseline (393.616 us; speedup 1.0000x reference)
//
#include <hip/hip_runtime.h>
#include <hip/hip_fp16.h>
#include <hip/hip_cooperative_groups.h>
#include <math.h>

namespace cg = cooperative_groups;

#define NREL    3
#define EDGES   200000
#define DIM     128
#define PASSES  5
#define UNITS   6250          // EDGES / 32
#define BJ      313           // ceil(UNITS / (4*PASSES))
#define JPER    (6 * BJ)      // (ro, bj) pairs per XCD slot
#define VBLOCKS (8 * JPER)    // 15024 virtual distmult blocks

#define NDRUG   8000
#define NDIS    18000
#define DRUG_ELEMS (NDRUG * DIM)             // 1,024,000
#define TOT_ELEMS  ((NDRUG + NDIS) * DIM)    // 3,328,000

typedef _Float16 half8 __attribute__((ext_vector_type(8)));

// ---------------- distmult inner body (shared by fused + fallback) --------
// R5: VGPR=36 proved source-level pipelines collapse. R6: all-vmem-as-
// inline-asm + hand-counted vmcnt gave distmult 48->~38us (e2e -10).
// Queue per iteration: [<=5 stores from prev iter], 10 idx, 2 W, vmcnt(2)
// (= all but newest 2 done -> idx+old stores drained), 10 row gathers,
// progressive vmcnt(8/6/4/2/0). Stores are inline asm so they are
// deterministically OLDER than the next iteration's waits.
__device__ __forceinline__ void distmult_body(
    int vb,
    const _Float16* __restrict__ tabs, const float* __restrict__ W,
    const int* __restrict__ drug_src, const int* __restrict__ dis_dst,
    const int* __restrict__ dis_src,  const int* __restrict__ drug_dst,
    float* __restrict__ part0, float* __restrict__ part1)
{
    const int slot  = vb & 7;       // XCD slot (stride 1024 preserves this)
    const int chunk = slot >> 2;    // 0..1 -> dims [64*chunk, +64)
    const int q     = slot & 3;     // 4 XCDs per chunk share the edge units
    const int j     = vb >> 3;
    const int ro    = j / BJ;       // 0..5 (0..2 fwd, 3..5 rev)
    const int bj    = j % BJ;

    const int eg   = threadIdx.x >> 3;  // 0..31 edge within pass
    const int lane = threadIdx.x & 7;   // 0..7: 8 halfs (16 B) per lane

    const _Float16* tabD = tabs;
    const _Float16* tabS = tabs + DRUG_ELEMS;
    const _Float16 *tabA, *tabB; const int *idxA, *idxB;
    if (ro < NREL) {
        tabA = tabD; tabB = tabS;
        idxA = drug_src + ro * EDGES;
        idxB = dis_dst  + ro * EDGES;
    } else {
        tabA = tabS; tabB = tabD;
        idxA = dis_src  + (ro - NREL) * EDGES;
        idxB = drug_dst + (ro - NREL) * EDGES;
    }

    const int off = chunk * 64 + lane * 8;            // element offset in row
    const _Float16* tA = tabA + off;                  // pre-offset bases
    const _Float16* tB = tabB + off;
    float* pbase = (chunk == 0 ? part0 : part1) + (size_t)ro * EDGES;

    // Stage 1: ALL 10 index loads in flight.
    int e[PASSES];
    bool valid[PASSES];
    int ia[PASSES], ib[PASSES];
    #pragma unroll
    for (int p = 0; p < PASSES; ++p) {
        const int u = q + 4 * (p + PASSES * bj);
        valid[p] = (u < UNITS);
        const int uc = valid[p] ? u : (UNITS - 1);
        e[p] = uc * 32 + eg;
        asm volatile("global_load_dword %0, %1, off"
                     : "=v"(ia[p]) : "v"(idxA + e[p]));
        asm volatile("global_load_dword %0, %1, off"
                     : "=v"(ib[p]) : "v"(idxB + e[p]));
    }

    // Stage 2: W loads (newest 2 in the queue).
    float4 wlo, whi;
    asm volatile("global_load_dwordx4 %0, %1, off"
                 : "=v"(wlo) : "v"(W + ro * DIM + off));
    asm volatile("global_load_dwordx4 %0, %1, off"
                 : "=v"(whi) : "v"(W + ro * DIM + off + 4));

    // All idx (and any older stores) done; W may still be outstanding.
    asm volatile("s_waitcnt vmcnt(2)");
    __builtin_amdgcn_sched_barrier(0);

    // Stage 3: ALL 10 row gathers in flight (12 outstanding with W).
    half8 a8[PASSES], b8[PASSES];
    #pragma unroll
    for (int p = 0; p < PASSES; ++p) {
        asm volatile("global_load_dwordx4 %0, %1, off"
                     : "=v"(a8[p]) : "v"(tA + ia[p] * DIM));
        asm volatile("global_load_dwordx4 %0, %1, off"
                     : "=v"(b8[p]) : "v"(tB + ib[p] * DIM));
    }

    // Stage 4: per-pass compute behind progressive counted waits.
    float res[PASSES];
#define DOT(p)                                                              \
    {                                                                       \
        float s = 0.0f;                                                     \
        s = fmaf((float)a8[p][0] * (float)b8[p][0], wlo.x, s);              \
        s = fmaf((float)a8[p][1] * (float)b8[p][1], wlo.y, s);              \
        s = fmaf((float)a8[p][2] * (float)b8[p][2], wlo.z, s);              \
        s = fmaf((float)a8[p][3] * (float)b8[p][3], wlo.w, s);              \
        s = fmaf((float)a8[p][4] * (float)b8[p][4], whi.x, s);              \
        s = fmaf((float)a8[p][5] * (float)b8[p][5], whi.y, s);              \
        s = fmaf((float)a8[p][6] * (float)b8[p][6], whi.z, s);              \
        s = fmaf((float)a8[p][7] * (float)b8[p][7], whi.w, s);              \
        s += __shfl_xor(s, 4, 64);                                          \
        s += __shfl_xor(s, 2, 64);                                          \
        s += __shfl_xor(s, 1, 64);                                          \
        res[p] = s;                                                         \
    }
    asm volatile("s_waitcnt vmcnt(8)");     // W.lo, W.hi, a0, b0 landed
    __builtin_amdgcn_sched_barrier(0);
    DOT(0)
    asm volatile("s_waitcnt vmcnt(6)");
    __builtin_amdgcn_sched_barrier(0);
    DOT(1)
    asm volatile("s_waitcnt vmcnt(4)");
    __builtin_amdgcn_sched_barrier(0);
    DOT(2)
    asm volatile("s_waitcnt vmcnt(2)");
    __builtin_amdgcn_sched_barrier(0);
    DOT(3)
    asm volatile("s_waitcnt vmcnt(0)");
    __builtin_amdgcn_sched_barrier(0);
    DOT(4)
#undef DOT

    // Stage 5: asm stores (ordered; never corrupt the next iter's counts).
    if (lane == 0) {
        #pragma unroll
        for (int p = 0; p < PASSES; ++p)
            if (valid[p])
                asm volatile("global_store_dword %0, %1, off"
                             :: "v"(pbase + e[p]), "v"(res[p]));
    }
}

// --------------- fused cooperative kernel: convert|distmult|reduce --------
// R7(this): the 3-kernel stream shows ~28us of inter-dispatch gaps
// (sum-of-dispatches 87us vs dur 115.5us). One cooperative launch removes
// 2 gaps; grid=1024=4 blocks/CU (launch_bounds cap -> co-residency
// guaranteed); stride 1024%8==0 preserves XCD chunk pinning.
__global__ __launch_bounds__(256, 4) void fused_all(
    const float* __restrict__ drug, const float* __restrict__ dis,
    const float* __restrict__ W,
    const int* __restrict__ drug_src, const int* __restrict__ dis_dst,
    const int* __restrict__ dis_src,  const int* __restrict__ drug_dst,
    _Float16* __restrict__ tabs, float* __restrict__ part1,
    float* __restrict__ out)
{
    cg::grid_group grid = cg::this_grid();
    const int tid = blockIdx.x * 256 + threadIdx.x;
    const int nthr = gridDim.x * 256;

    // ---- Phase 1: fp32 -> fp16 table conversion (plain stores: keep L2 hot)
    {
        const int nd8 = DRUG_ELEMS / 8, nt8 = TOT_ELEMS / 8;
        for (int i = tid; i < nt8; i += nthr) {
            const float4* s; int j;
            if (i < nd8) { s = (const float4*)drug; j = i * 2; }
            else         { s = (const float4*)dis;  j = (i - nd8) * 2; }
            const float4 x = s[j], y = s[j + 1];
            half8 h;
            h[0] = (_Float16)x.x; h[1] = (_Float16)x.y;
            h[2] = (_Float16)x.z; h[3] = (_Float16)x.w;
            h[4] = (_Float16)y.x; h[5] = (_Float16)y.y;
            h[6] = (_Float16)y.z; h[7] = (_Float16)y.w;
            ((half8*)tabs)[i] = h;
        }
    }
    grid.sync();

    // ---- Phase 2: distmult over virtual blocks --------------------------
    for (int vb = blockIdx.x; vb < VBLOCKS; vb += gridDim.x)
        distmult_body(vb, tabs, W, drug_src, dis_dst, dis_src, drug_dst,
                      out, part1);
    grid.sync();

    // ---- Phase 3: out = sigmoid(out + part1) ----------------------------
    {
        const int n4 = (6 * EDGES) / 4;
        for (int i = tid; i < n4; i += nthr) {
            float4 v = ((const float4*)out)[i];
            const float4 a = ((const float4*)part1)[i];
            v.x = 1.0f / (1.0f + __expf(-(v.x + a.x)));
            v.y = 1.0f / (1.0f + __expf(-(v.y + a.y)));
            v.z = 1.0f / (1.0f + __expf(-(v.z + a.z)));
            v.w = 1.0f / (1.0f + __expf(-(v.w + a.w)));
            ((float4*)out)[i] = v;
        }
    }
}

// ---------------- fallback: proven 3-kernel path --------------------------
__global__ __launch_bounds__(256) void convert_fp16(
    const float* __restrict__ drug, const float* __restrict__ dis,
    _Float16* __restrict__ o)
{
    const int i = blockIdx.x * 256 + threadIdx.x;
    const int nd8 = DRUG_ELEMS / 8, nt8 = TOT_ELEMS / 8;
    if (i >= nt8) return;
    const float4* s; int j;
    if (i < nd8) { s = (const float4*)drug; j = i * 2; }
    else         { s = (const float4*)dis;  j = (i - nd8) * 2; }
    const float4 x = s[j], y = s[j + 1];
    half8 h;
    h[0] = (_Float16)x.x; h[1] = (_Float16)x.y;
    h[2] = (_Float16)x.z; h[3] = (_Float16)x.w;
    h[4] = (_Float16)y.x; h[5] = (_Float16)y.y;
    h[6] = (_Float16)y.z; h[7] = (_Float16)y.w;
    ((half8*)o)[i] = h;
}

__global__ __launch_bounds__(256, 4) void distmult_fp16(
    const _Float16* __restrict__ tabs, const float* __restrict__ W,
    const int* __restrict__ drug_src, const int* __restrict__ dis_dst,
    const int* __restrict__ dis_src,  const int* __restrict__ drug_dst,
    float* __restrict__ part0, float* __restrict__ part1)
{
    distmult_body(blockIdx.x, tabs, W, drug_src, dis_dst, dis_src, drug_dst,
                  part0, part1);
}

__global__ __launch_bounds__(256) void reduce_sigmoid(
    const float* __restrict__ part1, float* __restrict__ out)
{
    const int i = blockIdx.x * 256 + threadIdx.x;
    if (i >= (6 * EDGES) / 4) return;
    float4 v = ((const float4*)out)[i];
    const float4 a = ((const float4*)part1)[i];
    v.x = 1.0f / (1.0f + __expf(-(v.x + a.x)));
    v.y = 1.0f / (1.0f + __expf(-(v.y + a.y)));
    v.z = 1.0f / (1.0f + __expf(-(v.z + a.z)));
    v.w = 1.0f / (1.0f + __expf(-(v.w + a.w)));
    ((float4*)out)[i] = v;
}

// ---- fallback (fp32 atomic path) if ws is too small ----
__global__ __launch_bounds__(256) void distmult_atomic(
    const float* __restrict__ h_drug, const float* __restrict__ h_disease,
    const float* __restrict__ W,
    const int* __restrict__ drug_src, const int* __restrict__ dis_dst,
    const int* __restrict__ dis_src, const int* __restrict__ drug_dst,
    float* __restrict__ out)
{
    const int b = blockIdx.x;
    const int slot = b & 7, chunk = slot >> 1, half = slot & 1;
    const int j = b >> 3;
    const int ro = j / 625, batch = j % 625;
    const int eg = threadIdx.x >> 3, lane = threadIdx.x & 7;

    const float* tabA; const float* tabB;
    const int* idxA; const int* idxB;
    if (ro < NREL) {
        tabA = h_drug;    tabB = h_disease;
        idxA = drug_src + (size_t)ro * EDGES;
        idxB = dis_dst  + (size_t)ro * EDGES;
    } else {
        tabA = h_disease; tabB = h_drug;
        idxA = dis_src  + (size_t)(ro - NREL) * EDGES;
        idxB = drug_dst + (size_t)(ro - NREL) * EDGES;
    }
    const int off = chunk * 32;
    const float4 w4 = ((const float4*)(W + (size_t)ro * DIM + off))[lane];

    #pragma unroll
    for (int p = 0; p < 5; ++p) {
        const int e = batch * 320 + p * 64 + half * 32 + eg;
        const int ia = __builtin_nontemporal_load(idxA + e);
        const int ib = __builtin_nontemporal_load(idxB + e);
        const float4 a4 = ((const float4*)(tabA + (size_t)ia * DIM + off))[lane];
        const float4 b4 = ((const float4*)(tabB + (size_t)ib * DIM + off))[lane];
        float s = a4.x * w4.x * b4.x + a4.y * w4.y * b4.y
                + a4.z * w4.z * b4.z + a4.w * w4.w * b4.w;
        s += __shfl_xor(s, 4, 64);
        s += __shfl_xor(s, 2, 64);
        s += __shfl_xor(s, 1, 64);
        if (lane == 0) atomicAdd(&out[(size_t)ro * EDGES + e], s);
    }
}

__global__ __launch_bounds__(256) void sigmoid_inplace(float* __restrict__ out)
{
    const int i = blockIdx.x * 256 + threadIdx.x;
    if (i >= (6 * EDGES) / 4) return;
    float4 v = ((float4*)out)[i];
    v.x = 1.0f / (1.0f + __expf(-v.x));
    v.y = 1.0f / (1.0f + __expf(-v.y));
    v.z = 1.0f / (1.0f + __expf(-v.z));
    v.w = 1.0f / (1.0f + __expf(-v.w));
    ((float4*)out)[i] = v;
}

extern "C" void kernel_launch(void* const* d_in, const int* in_sizes, int n_in,
                              void* d_out, int out_size, void* d_ws, size_t ws_size,
                              hipStream_t stream) {
    const float* h_drug    = (const float*)d_in[0];
    const float* h_disease = (const float*)d_in[1];
    const float* W         = (const float*)d_in[2];
    const int*   drug_src  = (const int*)d_in[3];
    const int*   dis_dst   = (const int*)d_in[4];
    const int*   dis_src   = (const int*)d_in[5];
    const int*   drug_dst  = (const int*)d_in[6];
    float*       out       = (float*)d_out;

    const int n4 = (6 * EDGES) / 4;                       // 300000
    const size_t tab_bytes = (size_t)TOT_ELEMS * 2;       // 6,656,000
    const size_t ws_need   = tab_bytes + (size_t)6 * EDGES * sizeof(float); // 11.46 MB

    if (ws_size >= ws_need) {
        _Float16* tabs  = (_Float16*)d_ws;
        float*    part1 = (float*)((char*)d_ws + tab_bytes);

        void* args[] = { (void*)&h_drug, (void*)&h_disease, (void*)&W,
                         (void*)&drug_src, (void*)&dis_dst,
                         (void*)&dis_src, (void*)&drug_dst,
                         (void*)&tabs, (void*)&part1, (void*)&out };
        hipError_t err = hipLaunchCooperativeKernel(
            (const void*)fused_all, dim3(1024), dim3(256), args, 0, stream);

        if (err != hipSuccess) {
            // proven 3-kernel path
            convert_fp16<<<(TOT_ELEMS / 8 + 255) / 256, 256, 0, stream>>>(
                h_drug, h_disease, tabs);
            distmult_fp16<<<VBLOCKS, 256, 0, stream>>>(
                tabs, W, drug_src, dis_dst, dis_src, drug_dst, out, part1);
            reduce_sigmoid<<<(n4 + 255) / 256, 256, 0, stream>>>(part1, out);
        }
    } else {
        (void)hipMemsetAsync(out, 0, (size_t)6 * EDGES * sizeof(float), stream);
        distmult_atomic<<<8 * 6 * 625, 256, 0, stream>>>(
            h_drug, h_disease, W, drug_src, dis_dst, dis_src, drug_dst, out);
        sigmoid_inplace<<<(n4 + 255) / 256, 256, 0, stream>>>(out);
    }
}

// Round 5
// 118.981 us; speedup vs baseline: 3.3082x; 3.3082x over previous
//
#include <hip/hip_runtime.h>
#include <hip/hip_fp16.h>
#include <math.h>

#define NREL    3
#define EDGES   200000
#define DIM     128
#define PASSES  5
#define UNITS2  12500         // EDGES / 16  (16 edges per pass-unit)
#define BJ2     313           // ceil(UNITS2 / (8*PASSES))
#define VBLOCKS (8 * 6 * BJ2) // 15024 blocks

#define NDRUG   8000
#define NDIS    18000
#define DRUG_ELEMS (NDRUG * DIM)             // 1,024,000
#define TOT_ELEMS  ((NDRUG + NDIS) * DIM)    // 3,328,000

typedef _Float16 half8 __attribute__((ext_vector_type(8)));

// Pre-pass: fp32 tables -> fp16 (concatenated [drug | disease]) in d_ws.
__global__ __launch_bounds__(256) void convert_fp16(
    const float* __restrict__ drug, const float* __restrict__ dis,
    _Float16* __restrict__ o)
{
    const int i = blockIdx.x * 256 + threadIdx.x;   // half8 index
    const int nd8 = DRUG_ELEMS / 8, nt8 = TOT_ELEMS / 8;
    if (i >= nt8) return;
    const float4* s; int j;
    if (i < nd8) { s = (const float4*)drug; j = i * 2; }
    else         { s = (const float4*)dis;  j = (i - nd8) * 2; }
    const float4 x = s[j], y = s[j + 1];
    half8 h;
    h[0] = (_Float16)x.x; h[1] = (_Float16)x.y;
    h[2] = (_Float16)x.z; h[3] = (_Float16)x.w;
    h[4] = (_Float16)y.x; h[5] = (_Float16)y.y;
    h[6] = (_Float16)y.z; h[7] = (_Float16)y.w;
    ((half8*)o)[i] = h;
}

// R6: inline-asm vmcnt pipeline gave distmult 48->~38us. R7: coop fusion
// catastrophically regressed (310us, cause unresolved — suspect coop
// dispatcher breaking blockIdx%8->XCD pinning) => reverted. R8(this):
// merge the chunk split instead — one block computes the FULL 128-dim dot
// (16 lanes x 16B = whole 256B fp16 row), applies sigmoid inline, stores
// the final value. Eliminates reduce_sigmoid + 1 launch gap + both part
// buffers + the out RMW. Accepted cost: full 6.66MB table per XCD L2
// (>4MiB) -> ~60% L2 hit, misses L3-resident (HBM counters must stay flat).
// Pipeline identical to R6: 10 idx, 2 W, vmcnt(2), 10 gathers, 8/6/4/2/0.
__global__ __launch_bounds__(256, 4) void distmult_full(
    const _Float16* __restrict__ tabs,   // [drug fp16 | disease fp16]
    const float* __restrict__ W,
    const int* __restrict__ drug_src, const int* __restrict__ dis_dst,
    const int* __restrict__ dis_src,  const int* __restrict__ drug_dst,
    float* __restrict__ out)
{
    const int b    = blockIdx.x;
    const int q    = b & 7;         // 8-way unit interleave, XCD-pinned
    const int j    = b >> 3;
    const int ro   = j / BJ2;       // 0..5 (0..2 fwd, 3..5 rev)
    const int bj   = j % BJ2;

    const int eg   = threadIdx.x >> 4;   // 0..15 edge within pass
    const int lane = threadIdx.x & 15;   // 0..15: 8 halfs (16 B) per lane

    const _Float16* tabD = tabs;
    const _Float16* tabS = tabs + DRUG_ELEMS;
    const _Float16 *tabA, *tabB; const int *idxA, *idxB;
    if (ro < NREL) {
        tabA = tabD; tabB = tabS;
        idxA = drug_src + ro * EDGES;
        idxB = dis_dst  + ro * EDGES;
    } else {
        tabA = tabS; tabB = tabD;
        idxA = dis_src  + (ro - NREL) * EDGES;
        idxB = drug_dst + (ro - NREL) * EDGES;
    }

    const int off = lane * 8;            // element offset in row (0..120)
    const _Float16* tA = tabA + off;     // pre-offset bases
    const _Float16* tB = tabB + off;
    float* obase = out + (size_t)ro * EDGES;

    // ---- Stage 1: issue ALL 10 index loads (oldest in the vmcnt queue). ----
    int e[PASSES];
    bool valid[PASSES];
    int ia[PASSES], ib[PASSES];
    #pragma unroll
    for (int p = 0; p < PASSES; ++p) {
        const int u = q + 8 * (p + PASSES * bj);
        valid[p] = (u < UNITS2);
        const int uc = valid[p] ? u : (UNITS2 - 1);
        e[p] = uc * 16 + eg;
        asm volatile("global_load_dword %0, %1, off"
                     : "=v"(ia[p]) : "v"(idxA + e[p]));
        asm volatile("global_load_dword %0, %1, off"
                     : "=v"(ib[p]) : "v"(idxB + e[p]));
    }

    // ---- Stage 2: W loads (newest 2; lane*8 floats cover the full row). --
    float4 wlo, whi;
    asm volatile("global_load_dwordx4 %0, %1, off"
                 : "=v"(wlo) : "v"(W + ro * DIM + off));
    asm volatile("global_load_dwordx4 %0, %1, off"
                 : "=v"(whi) : "v"(W + ro * DIM + off + 4));

    // All 10 idx done; W's 2 loads may remain outstanding.
    asm volatile("s_waitcnt vmcnt(2)");
    __builtin_amdgcn_sched_barrier(0);

    // ---- Stage 3: ALL 10 row gathers in flight (12 outstanding with W). ----
    half8 a8[PASSES], b8[PASSES];
    #pragma unroll
    for (int p = 0; p < PASSES; ++p) {
        asm volatile("global_load_dwordx4 %0, %1, off"
                     : "=v"(a8[p]) : "v"(tA + ia[p] * DIM));
        asm volatile("global_load_dwordx4 %0, %1, off"
                     : "=v"(b8[p]) : "v"(tB + ib[p] * DIM));
    }

    // ---- Stage 4: per-pass compute behind progressive counted waits. ----
    // Queue (oldest->newest): W.lo, W.hi, a0,b0,a1,b1,...,a4,b4.
    float res[PASSES];
#define DOT(p)                                                              \
    {                                                                       \
        float s = 0.0f;                                                     \
        s = fmaf((float)a8[p][0] * (float)b8[p][0], wlo.x, s);              \
        s = fmaf((float)a8[p][1] * (float)b8[p][1], wlo.y, s);              \
        s = fmaf((float)a8[p][2] * (float)b8[p][2], wlo.z, s);              \
        s = fmaf((float)a8[p][3] * (float)b8[p][3], wlo.w, s);              \
        s = fmaf((float)a8[p][4] * (float)b8[p][4], whi.x, s);              \
        s = fmaf((float)a8[p][5] * (float)b8[p][5], whi.y, s);              \
        s = fmaf((float)a8[p][6] * (float)b8[p][6], whi.z, s);              \
        s = fmaf((float)a8[p][7] * (float)b8[p][7], whi.w, s);              \
        s += __shfl_xor(s, 8, 64);                                          \
        s += __shfl_xor(s, 4, 64);                                          \
        s += __shfl_xor(s, 2, 64);                                          \
        s += __shfl_xor(s, 1, 64);                                          \
        res[p] = s;                                                         \
    }
    asm volatile("s_waitcnt vmcnt(8)");     // W.lo, W.hi, a0, b0 landed
    __builtin_amdgcn_sched_barrier(0);
    DOT(0)
    asm volatile("s_waitcnt vmcnt(6)");
    __builtin_amdgcn_sched_barrier(0);
    DOT(1)
    asm volatile("s_waitcnt vmcnt(4)");
    __builtin_amdgcn_sched_barrier(0);
    DOT(2)
    asm volatile("s_waitcnt vmcnt(2)");
    __builtin_amdgcn_sched_barrier(0);
    DOT(3)
    asm volatile("s_waitcnt vmcnt(0)");
    __builtin_amdgcn_sched_barrier(0);
    DOT(4)
#undef DOT

    // ---- Stage 5: sigmoid + final store (nothing waits on these). ----
    if (lane == 0) {
        #pragma unroll
        for (int p = 0; p < PASSES; ++p)
            if (valid[p]) {
                const float v = 1.0f / (1.0f + __expf(-res[p]));
                __builtin_nontemporal_store(v, obase + e[p]);
            }
    }
}

// ---- fallback (fp32 atomic path) if ws is too small ----
__global__ __launch_bounds__(256) void distmult_atomic(
    const float* __restrict__ h_drug, const float* __restrict__ h_disease,
    const float* __restrict__ W,
    const int* __restrict__ drug_src, const int* __restrict__ dis_dst,
    const int* __restrict__ dis_src, const int* __restrict__ drug_dst,
    float* __restrict__ out)
{
    const int b = blockIdx.x;
    const int slot = b & 7, chunk = slot >> 1, half = slot & 1;
    const int j = b >> 3;
    const int ro = j / 625, batch = j % 625;
    const int eg = threadIdx.x >> 3, lane = threadIdx.x & 7;

    const float* tabA; const float* tabB;
    const int* idxA; const int* idxB;
    if (ro < NREL) {
        tabA = h_drug;    tabB = h_disease;
        idxA = drug_src + (size_t)ro * EDGES;
        idxB = dis_dst  + (size_t)ro * EDGES;
    } else {
        tabA = h_disease; tabB = h_drug;
        idxA = dis_src  + (size_t)(ro - NREL) * EDGES;
        idxB = drug_dst + (size_t)(ro - NREL) * EDGES;
    }
    const int off = chunk * 32;
    const float4 w4 = ((const float4*)(W + (size_t)ro * DIM + off))[lane];

    #pragma unroll
    for (int p = 0; p < 5; ++p) {
        const int e = batch * 320 + p * 64 + half * 32 + eg;
        const int ia = __builtin_nontemporal_load(idxA + e);
        const int ib = __builtin_nontemporal_load(idxB + e);
        const float4 a4 = ((const float4*)(tabA + (size_t)ia * DIM + off))[lane];
        const float4 b4 = ((const float4*)(tabB + (size_t)ib * DIM + off))[lane];
        float s = a4.x * w4.x * b4.x + a4.y * w4.y * b4.y
                + a4.z * w4.z * b4.z + a4.w * w4.w * b4.w;
        s += __shfl_xor(s, 4, 64);
        s += __shfl_xor(s, 2, 64);
        s += __shfl_xor(s, 1, 64);
        if (lane == 0) atomicAdd(&out[(size_t)ro * EDGES + e], s);
    }
}

__global__ __launch_bounds__(256) void sigmoid_inplace(float* __restrict__ out)
{
    const int i = blockIdx.x * 256 + threadIdx.x;
    if (i >= (6 * EDGES) / 4) return;
    float4 v = ((float4*)out)[i];
    v.x = 1.0f / (1.0f + __expf(-v.x));
    v.y = 1.0f / (1.0f + __expf(-v.y));
    v.z = 1.0f / (1.0f + __expf(-v.z));
    v.w = 1.0f / (1.0f + __expf(-v.w));
    ((float4*)out)[i] = v;
}

extern "C" void kernel_launch(void* const* d_in, const int* in_sizes, int n_in,
                              void* d_out, int out_size, void* d_ws, size_t ws_size,
                              hipStream_t stream) {
    const float* h_drug    = (const float*)d_in[0];
    const float* h_disease = (const float*)d_in[1];
    const float* W         = (const float*)d_in[2];
    const int*   drug_src  = (const int*)d_in[3];
    const int*   dis_dst   = (const int*)d_in[4];
    const int*   dis_src   = (const int*)d_in[5];
    const int*   drug_dst  = (const int*)d_in[6];
    float*       out       = (float*)d_out;

    const int n4 = (6 * EDGES) / 4;                       // 300000
    const size_t tab_bytes = (size_t)TOT_ELEMS * 2;       // 6,656,000

    if (ws_size >= tab_bytes) {
        _Float16* tabs = (_Float16*)d_ws;

        convert_fp16<<<(TOT_ELEMS / 8 + 255) / 256, 256, 0, stream>>>(
            h_drug, h_disease, tabs);
        distmult_full<<<VBLOCKS, 256, 0, stream>>>(
            tabs, W, drug_src, dis_dst, dis_src, drug_dst, out);
    } else {
        (void)hipMemsetAsync(out, 0, (size_t)6 * EDGES * sizeof(float), stream);
        distmult_atomic<<<8 * 6 * 625, 256, 0, stream>>>(
            h_drug, h_disease, W, drug_src, dis_dst, dis_src, drug_dst, out);
        sigmoid_inplace<<<(n4 + 255) / 256, 256, 0, stream>>>(out);
    }
}

// Round 6
// 114.434 us; speedup vs baseline: 3.4397x; 1.0397x over previous
//
#include <hip/hip_runtime.h>
#include <hip/hip_fp16.h>
#include <math.h>

#define NREL    3
#define EDGES   200000
#define DIM     128
#define PASSES  4
#define UNITS   6250          // EDGES / 32
#define BJ      391           // ceil(UNITS / (4*PASSES))
#define VBLOCKS (8 * 6 * BJ)  // 18768 blocks

#define NDRUG   8000
#define NDIS    18000
#define DRUG_ELEMS (NDRUG * DIM)             // 1,024,000
#define TOT_ELEMS  ((NDRUG + NDIS) * DIM)    // 3,328,000

typedef _Float16 half8 __attribute__((ext_vector_type(8)));

// Pre-pass: fp32 tables -> fp16 (concatenated [drug | disease]) in d_ws.
__global__ __launch_bounds__(256) void convert_fp16(
    const float* __restrict__ drug, const float* __restrict__ dis,
    _Float16* __restrict__ o)
{
    const int i = blockIdx.x * 256 + threadIdx.x;   // half8 index
    const int nd8 = DRUG_ELEMS / 8, nt8 = TOT_ELEMS / 8;
    if (i >= nt8) return;
    const float4* s; int j;
    if (i < nd8) { s = (const float4*)drug; j = i * 2; }
    else         { s = (const float4*)dis;  j = (i - nd8) * 2; }
    const float4 x = s[j], y = s[j + 1];
    half8 h;
    h[0] = (_Float16)x.x; h[1] = (_Float16)x.y;
    h[2] = (_Float16)x.z; h[3] = (_Float16)x.w;
    h[4] = (_Float16)y.x; h[5] = (_Float16)y.y;
    h[6] = (_Float16)y.z; h[7] = (_Float16)y.w;
    ((half8*)o)[i] = h;
}

// R6: inline-asm vmcnt pipeline, distmult 48->38us (e2e 115.5, proven).
// R7 (coop fusion, 310us) and R8 (full-dot merge, +13us on distmult from
// 6.6MB/XCD L2 thrash) both REGRESSED -> chunk split + 3-kernel structure
// is load-bearing; reverted to R6 exactly except:
// R9(this): PASSES 5->4 to fit VGPR<=64. HW occupancy steps at 64/128/256
// (m69): at ~76 VGPR we were stuck at 4 waves/SIMD; <=64 doubles resident
// waves (8/SIMD, 8 blocks/CU) -> 2x outstanding random L2 requests per CU.
// Budget: 8 gather dests(32) + W(8) + e(4) + res(4) + bases(6) + tmp ~6 = 58.
// Queue per block: 8 idx, 2 W, vmcnt(2), 8 gathers, vmcnt(6/4/2/0).
__global__ __launch_bounds__(256, 8) void distmult_fp16(
    const _Float16* __restrict__ tabs,   // [drug fp16 | disease fp16]
    const float* __restrict__ W,
    const int* __restrict__ drug_src, const int* __restrict__ dis_dst,
    const int* __restrict__ dis_src,  const int* __restrict__ drug_dst,
    float* __restrict__ part0,           // = d_out, chunk-0 partials
    float* __restrict__ part1)           // = ws,    chunk-1 partials
{
    const int b     = blockIdx.x;
    const int slot  = b & 7;        // XCD slot
    const int chunk = slot >> 2;    // 0..1 -> dims [64*chunk, +64)
    const int q     = slot & 3;     // 4 XCDs per chunk share the edge units
    const int j     = b >> 3;
    const int ro    = j / BJ;       // 0..5 (0..2 fwd, 3..5 rev)
    const int bj    = j % BJ;

    const int eg   = threadIdx.x >> 3;  // 0..31 edge within pass
    const int lane = threadIdx.x & 7;   // 0..7: 8 halfs (16 B) per lane

    const _Float16* tabD = tabs;
    const _Float16* tabS = tabs + DRUG_ELEMS;
    const _Float16 *tabA, *tabB; const int *idxA, *idxB;
    if (ro < NREL) {
        tabA = tabD; tabB = tabS;
        idxA = drug_src + ro * EDGES;
        idxB = dis_dst  + ro * EDGES;
    } else {
        tabA = tabS; tabB = tabD;
        idxA = dis_src  + (ro - NREL) * EDGES;
        idxB = drug_dst + (ro - NREL) * EDGES;
    }

    const int off = chunk * 64 + lane * 8;            // element offset in row
    const _Float16* tA = tabA + off;                  // pre-offset bases
    const _Float16* tB = tabB + off;
    float* pbase = (chunk == 0 ? part0 : part1) + (size_t)ro * EDGES;

    // ---- Stage 1: issue ALL 8 index loads (oldest in the vmcnt queue). ----
    int e[PASSES];
    bool valid[PASSES];
    int ia[PASSES], ib[PASSES];
    #pragma unroll
    for (int p = 0; p < PASSES; ++p) {
        const int u = q + 4 * (p + PASSES * bj);
        valid[p] = (u < UNITS);
        const int uc = valid[p] ? u : (UNITS - 1);
        e[p] = uc * 32 + eg;
        asm volatile("global_load_dword %0, %1, off"
                     : "=v"(ia[p]) : "v"(idxA + e[p]));
        asm volatile("global_load_dword %0, %1, off"
                     : "=v"(ib[p]) : "v"(idxB + e[p]));
    }

    // ---- Stage 2: W loads (newest 2 in the queue). ----
    float4 wlo, whi;
    asm volatile("global_load_dwordx4 %0, %1, off"
                 : "=v"(wlo) : "v"(W + ro * DIM + off));
    asm volatile("global_load_dwordx4 %0, %1, off"
                 : "=v"(whi) : "v"(W + ro * DIM + off + 4));

    // All 8 idx done; W's 2 loads may remain outstanding.
    asm volatile("s_waitcnt vmcnt(2)");
    __builtin_amdgcn_sched_barrier(0);

    // ---- Stage 3: ALL 8 row gathers in flight (10 outstanding with W). ----
    half8 a8[PASSES], b8[PASSES];
    #pragma unroll
    for (int p = 0; p < PASSES; ++p) {
        asm volatile("global_load_dwordx4 %0, %1, off"
                     : "=v"(a8[p]) : "v"(tA + ia[p] * DIM));
        asm volatile("global_load_dwordx4 %0, %1, off"
                     : "=v"(b8[p]) : "v"(tB + ib[p] * DIM));
    }

    // ---- Stage 4: per-pass compute behind progressive counted waits. ----
    // Queue (oldest->newest): W.lo, W.hi, a0,b0,a1,b1,a2,b2,a3,b3.
    float res[PASSES];
#define DOT(p)                                                              \
    {                                                                       \
        float s = 0.0f;                                                     \
        s = fmaf((float)a8[p][0] * (float)b8[p][0], wlo.x, s);              \
        s = fmaf((float)a8[p][1] * (float)b8[p][1], wlo.y, s);              \
        s = fmaf((float)a8[p][2] * (float)b8[p][2], wlo.z, s);              \
        s = fmaf((float)a8[p][3] * (float)b8[p][3], wlo.w, s);              \
        s = fmaf((float)a8[p][4] * (float)b8[p][4], whi.x, s);              \
        s = fmaf((float)a8[p][5] * (float)b8[p][5], whi.y, s);              \
        s = fmaf((float)a8[p][6] * (float)b8[p][6], whi.z, s);              \
        s = fmaf((float)a8[p][7] * (float)b8[p][7], whi.w, s);              \
        s += __shfl_xor(s, 4, 64);                                          \
        s += __shfl_xor(s, 2, 64);                                          \
        s += __shfl_xor(s, 1, 64);                                          \
        res[p] = s;                                                         \
    }
    asm volatile("s_waitcnt vmcnt(6)");     // W.lo, W.hi, a0, b0 landed
    __builtin_amdgcn_sched_barrier(0);
    DOT(0)
    asm volatile("s_waitcnt vmcnt(4)");
    __builtin_amdgcn_sched_barrier(0);
    DOT(1)
    asm volatile("s_waitcnt vmcnt(2)");
    __builtin_amdgcn_sched_barrier(0);
    DOT(2)
    asm volatile("s_waitcnt vmcnt(0)");
    __builtin_amdgcn_sched_barrier(0);
    DOT(3)
#undef DOT

    // ---- Stage 5: stores last (nothing waits on them afterwards). ----
    if (lane == 0) {
        #pragma unroll
        for (int p = 0; p < PASSES; ++p)
            if (valid[p])
                __builtin_nontemporal_store(res[p], pbase + e[p]);
    }
}

// Pass 3: out = sigmoid(out + part1), streaming.
__global__ __launch_bounds__(256) void reduce_sigmoid(
    const float* __restrict__ part1, float* __restrict__ out)
{
    const int i = blockIdx.x * 256 + threadIdx.x;     // float4 index
    if (i >= (6 * EDGES) / 4) return;
    float4 v = ((const float4*)out)[i];
    const float4 a = ((const float4*)part1)[i];
    v.x = 1.0f / (1.0f + __expf(-(v.x + a.x)));
    v.y = 1.0f / (1.0f + __expf(-(v.y + a.y)));
    v.z = 1.0f / (1.0f + __expf(-(v.z + a.z)));
    v.w = 1.0f / (1.0f + __expf(-(v.w + a.w)));
    ((float4*)out)[i] = v;
}

// ---- fallback (fp32 atomic path) if ws is too small ----
__global__ __launch_bounds__(256) void distmult_atomic(
    const float* __restrict__ h_drug, const float* __restrict__ h_disease,
    const float* __restrict__ W,
    const int* __restrict__ drug_src, const int* __restrict__ dis_dst,
    const int* __restrict__ dis_src, const int* __restrict__ drug_dst,
    float* __restrict__ out)
{
    const int b = blockIdx.x;
    const int slot = b & 7, chunk = slot >> 1, half = slot & 1;
    const int j = b >> 3;
    const int ro = j / 625, batch = j % 625;
    const int eg = threadIdx.x >> 3, lane = threadIdx.x & 7;

    const float* tabA; const float* tabB;
    const int* idxA; const int* idxB;
    if (ro < NREL) {
        tabA = h_drug;    tabB = h_disease;
        idxA = drug_src + (size_t)ro * EDGES;
        idxB = dis_dst  + (size_t)ro * EDGES;
    } else {
        tabA = h_disease; tabB = h_drug;
        idxA = dis_src  + (size_t)(ro - NREL) * EDGES;
        idxB = drug_dst + (size_t)(ro - NREL) * EDGES;
    }
    const int off = chunk * 32;
    const float4 w4 = ((const float4*)(W + (size_t)ro * DIM + off))[lane];

    #pragma unroll
    for (int p = 0; p < 5; ++p) {
        const int e = batch * 320 + p * 64 + half * 32 + eg;
        const int ia = __builtin_nontemporal_load(idxA + e);
        const int ib = __builtin_nontemporal_load(idxB + e);
        const float4 a4 = ((const float4*)(tabA + (size_t)ia * DIM + off))[lane];
        const float4 b4 = ((const float4*)(tabB + (size_t)ib * DIM + off))[lane];
        float s = a4.x * w4.x * b4.x + a4.y * w4.y * b4.y
                + a4.z * w4.z * b4.z + a4.w * w4.w * b4.w;
        s += __shfl_xor(s, 4, 64);
        s += __shfl_xor(s, 2, 64);
        s += __shfl_xor(s, 1, 64);
        if (lane == 0) atomicAdd(&out[(size_t)ro * EDGES + e], s);
    }
}

__global__ __launch_bounds__(256) void sigmoid_inplace(float* __restrict__ out)
{
    const int i = blockIdx.x * 256 + threadIdx.x;
    if (i >= (6 * EDGES) / 4) return;
    float4 v = ((float4*)out)[i];
    v.x = 1.0f / (1.0f + __expf(-v.x));
    v.y = 1.0f / (1.0f + __expf(-v.y));
    v.z = 1.0f / (1.0f + __expf(-v.z));
    v.w = 1.0f / (1.0f + __expf(-v.w));
    ((float4*)out)[i] = v;
}

extern "C" void kernel_launch(void* const* d_in, const int* in_sizes, int n_in,
                              void* d_out, int out_size, void* d_ws, size_t ws_size,
                              hipStream_t stream) {
    const float* h_drug    = (const float*)d_in[0];
    const float* h_disease = (const float*)d_in[1];
    const float* W         = (const float*)d_in[2];
    const int*   drug_src  = (const int*)d_in[3];
    const int*   dis_dst   = (const int*)d_in[4];
    const int*   dis_src   = (const int*)d_in[5];
    const int*   drug_dst  = (const int*)d_in[6];
    float*       out       = (float*)d_out;

    const int n4 = (6 * EDGES) / 4;                       // 300000
    const size_t tab_bytes = (size_t)TOT_ELEMS * 2;       // 6,656,000
    const size_t ws_need   = tab_bytes + (size_t)6 * EDGES * sizeof(float); // 11.46 MB

    if (ws_size >= ws_need) {
        _Float16* tabs  = (_Float16*)d_ws;
        float*    part1 = (float*)((char*)d_ws + tab_bytes);

        convert_fp16<<<(TOT_ELEMS / 8 + 255) / 256, 256, 0, stream>>>(
            h_drug, h_disease, tabs);
        distmult_fp16<<<VBLOCKS, 256, 0, stream>>>(
            tabs, W, drug_src, dis_dst, dis_src, drug_dst, out, part1);
        reduce_sigmoid<<<(n4 + 255) / 256, 256, 0, stream>>>(part1, out);
    } else {
        (void)hipMemsetAsync(out, 0, (size_t)6 * EDGES * sizeof(float), stream);
        distmult_atomic<<<8 * 6 * 625, 256, 0, stream>>>(
            h_drug, h_disease, W, drug_src, dis_dst, dis_src, drug_dst, out);
        sigmoid_inplace<<<(n4 + 255) / 256, 256, 0, stream>>>(out);
    }
}

// Round 7
// 112.596 us; speedup vs baseline: 3.4958x; 1.0163x over previous
//
#include <hip/hip_runtime.h>
#include <hip/hip_fp16.h>
#include <math.h>

#define NREL    3
#define EDGES   200000
#define DIM     128
#define PASSES  4
#define UNITS   6250          // EDGES / 32
#define BJ      391           // ceil(UNITS / (4*PASSES))
#define VBLOCKS (8 * 6 * BJ)  // 18768 blocks

#define NDRUG   8000
#define NDIS    18000
#define DRUG_ELEMS (NDRUG * DIM)             // 1,024,000
#define TOT_ELEMS  ((NDRUG + NDIS) * DIM)    // 3,328,000

typedef _Float16 half8 __attribute__((ext_vector_type(8)));

// Pre-pass: fp32 tables -> fp16 (concatenated [drug | disease]) in d_ws.
__global__ __launch_bounds__(256) void convert_fp16(
    const float* __restrict__ drug, const float* __restrict__ dis,
    _Float16* __restrict__ o)
{
    const int i = blockIdx.x * 256 + threadIdx.x;   // half8 index
    const int nd8 = DRUG_ELEMS / 8, nt8 = TOT_ELEMS / 8;
    if (i >= nt8) return;
    const float4* s; int j;
    if (i < nd8) { s = (const float4*)drug; j = i * 2; }
    else         { s = (const float4*)dis;  j = (i - nd8) * 2; }
    const float4 x = s[j], y = s[j + 1];
    half8 h;
    h[0] = (_Float16)x.x; h[1] = (_Float16)x.y;
    h[2] = (_Float16)x.z; h[3] = (_Float16)x.w;
    h[4] = (_Float16)y.x; h[5] = (_Float16)y.y;
    h[6] = (_Float16)y.z; h[7] = (_Float16)y.w;
    ((half8*)o)[i] = h;
}

// History: R6 asm-vmcnt pipeline 48->43us. R7 coop fusion (310us) and R8
// full-dot merge (L2 thrash) regressed -> 3-kernel + chunk split is
// load-bearing. R9: PASSES 5->4 + 8 blocks/CU: NULL vs R6 (43us both) =>
// neither wave-MLP nor occupancy is the limiter; suspect TA address-
// processing (idx loads are 8x redundant: 8 lanes load the same dword).
// R10(this): ONE idx load per wave covers all 4 passes x 8 edge-groups
// (lanes 0-31 idxA, lanes 32-63 idxB), distributed by __shfl. Cuts per-wave
// vmem instrs 23->16 and TA addr work ~40%. Discriminates TA-bound (-8us)
// vs scattered-L2-request-bound (null -> roofline).
// Queue: 1 idx, 2 W, vmcnt(2), shuffles, 8 gathers, vmcnt(6/4/2/0).
__global__ __launch_bounds__(256, 8) void distmult_fp16(
    const _Float16* __restrict__ tabs,   // [drug fp16 | disease fp16]
    const float* __restrict__ W,
    const int* __restrict__ drug_src, const int* __restrict__ dis_dst,
    const int* __restrict__ dis_src,  const int* __restrict__ drug_dst,
    float* __restrict__ part0,           // = d_out, chunk-0 partials
    float* __restrict__ part1)           // = ws,    chunk-1 partials
{
    const int b     = blockIdx.x;
    const int slot  = b & 7;        // XCD slot
    const int chunk = slot >> 2;    // 0..1 -> dims [64*chunk, +64)
    const int q     = slot & 3;     // 4 XCDs per chunk share the edge units
    const int j     = b >> 3;
    const int ro    = j / BJ;       // 0..5 (0..2 fwd, 3..5 rev)
    const int bj    = j % BJ;

    const int eg   = threadIdx.x >> 3;  // 0..31 edge-group within block
    const int lane = threadIdx.x & 7;   // 0..7: 8 halfs (16 B) per lane
    const int wl   = threadIdx.x & 63;  // lane within wave
    const int wave = threadIdx.x >> 6;  // 0..3
    const int g    = wl >> 3;           // 0..7: edge-group within wave

    const _Float16* tabD = tabs;
    const _Float16* tabS = tabs + DRUG_ELEMS;
    const _Float16 *tabA, *tabB; const int *idxA, *idxB;
    if (ro < NREL) {
        tabA = tabD; tabB = tabS;
        idxA = drug_src + ro * EDGES;
        idxB = dis_dst  + ro * EDGES;
    } else {
        tabA = tabS; tabB = tabD;
        idxA = dis_src  + (ro - NREL) * EDGES;
        idxB = drug_dst + (ro - NREL) * EDGES;
    }

    const int off = chunk * 64 + lane * 8;            // element offset in row
    const _Float16* tA = tabA + off;                  // pre-offset bases
    const _Float16* tB = tabB + off;
    float* pbase = (chunk == 0 ? part0 : part1) + (size_t)ro * EDGES;

    // ---- Stage 1: ONE idx load per wave. Lane wl<32 loads idxA for
    // pass p_ld=(wl&31)>>3, edge-group (wave*8 + (wl&7)); wl>=32 same for
    // idxB. Tail units clamp to UNITS-1 (same value as the scalar path).
    int e[PASSES];
    bool valid[PASSES];
    #pragma unroll
    for (int p = 0; p < PASSES; ++p) {
        const int u = q + 4 * (p + PASSES * bj);
        valid[p] = (u < UNITS);
        const int uc = valid[p] ? u : (UNITS - 1);
        e[p] = uc * 32 + eg;
    }
    int raw;
    {
        const int p_ld = (wl & 31) >> 3;
        const int u_ld = q + 4 * (p_ld + PASSES * bj);
        const int uc_ld = (u_ld < UNITS) ? u_ld : (UNITS - 1);
        const int e_ld = uc_ld * 32 + wave * 8 + (wl & 7);
        const int* src = (wl < 32) ? (idxA + e_ld) : (idxB + e_ld);
        asm volatile("global_load_dword %0, %1, off"
                     : "=v"(raw) : "v"(src));
    }

    // ---- Stage 2: W loads (newest 2 in the queue). ----
    float4 wlo, whi;
    asm volatile("global_load_dwordx4 %0, %1, off"
                 : "=v"(wlo) : "v"(W + ro * DIM + off));
    asm volatile("global_load_dwordx4 %0, %1, off"
                 : "=v"(whi) : "v"(W + ro * DIM + off + 4));

    // idx load done (W's 2 loads may remain outstanding).
    asm volatile("s_waitcnt vmcnt(2)");
    __builtin_amdgcn_sched_barrier(0);

    // ---- Stage 2b: distribute indices to consumers via wave shuffles. ----
    int ia[PASSES], ib[PASSES];
    #pragma unroll
    for (int p = 0; p < PASSES; ++p) {
        ia[p] = __shfl(raw, p * 8 + g, 64);
        ib[p] = __shfl(raw, 32 + p * 8 + g, 64);
    }

    // ---- Stage 3: ALL 8 row gathers in flight (10 outstanding with W). ----
    half8 a8[PASSES], b8[PASSES];
    #pragma unroll
    for (int p = 0; p < PASSES; ++p) {
        asm volatile("global_load_dwordx4 %0, %1, off"
                     : "=v"(a8[p]) : "v"(tA + ia[p] * DIM));
        asm volatile("global_load_dwordx4 %0, %1, off"
                     : "=v"(b8[p]) : "v"(tB + ib[p] * DIM));
    }

    // ---- Stage 4: per-pass compute behind progressive counted waits. ----
    // Queue (oldest->newest): W.lo, W.hi, a0,b0,a1,b1,a2,b2,a3,b3.
    float res[PASSES];
#define DOT(p)                                                              \
    {                                                                       \
        float s = 0.0f;                                                     \
        s = fmaf((float)a8[p][0] * (float)b8[p][0], wlo.x, s);              \
        s = fmaf((float)a8[p][1] * (float)b8[p][1], wlo.y, s);              \
        s = fmaf((float)a8[p][2] * (float)b8[p][2], wlo.z, s);              \
        s = fmaf((float)a8[p][3] * (float)b8[p][3], wlo.w, s);              \
        s = fmaf((float)a8[p][4] * (float)b8[p][4], whi.x, s);              \
        s = fmaf((float)a8[p][5] * (float)b8[p][5], whi.y, s);              \
        s = fmaf((float)a8[p][6] * (float)b8[p][6], whi.z, s);              \
        s = fmaf((float)a8[p][7] * (float)b8[p][7], whi.w, s);              \
        s += __shfl_xor(s, 4, 64);                                          \
        s += __shfl_xor(s, 2, 64);                                          \
        s += __shfl_xor(s, 1, 64);                                          \
        res[p] = s;                                                         \
    }
    asm volatile("s_waitcnt vmcnt(6)");     // W.lo, W.hi, a0, b0 landed
    __builtin_amdgcn_sched_barrier(0);
    DOT(0)
    asm volatile("s_waitcnt vmcnt(4)");
    __builtin_amdgcn_sched_barrier(0);
    DOT(1)
    asm volatile("s_waitcnt vmcnt(2)");
    __builtin_amdgcn_sched_barrier(0);
    DOT(2)
    asm volatile("s_waitcnt vmcnt(0)");
    __builtin_amdgcn_sched_barrier(0);
    DOT(3)
#undef DOT

    // ---- Stage 5: stores last (nothing waits on them afterwards). ----
    if (lane == 0) {
        #pragma unroll
        for (int p = 0; p < PASSES; ++p)
            if (valid[p])
                __builtin_nontemporal_store(res[p], pbase + e[p]);
    }
}

// Pass 3: out = sigmoid(out + part1), streaming.
__global__ __launch_bounds__(256) void reduce_sigmoid(
    const float* __restrict__ part1, float* __restrict__ out)
{
    const int i = blockIdx.x * 256 + threadIdx.x;     // float4 index
    if (i >= (6 * EDGES) / 4) return;
    float4 v = ((const float4*)out)[i];
    const float4 a = ((const float4*)part1)[i];
    v.x = 1.0f / (1.0f + __expf(-(v.x + a.x)));
    v.y = 1.0f / (1.0f + __expf(-(v.y + a.y)));
    v.z = 1.0f / (1.0f + __expf(-(v.z + a.z)));
    v.w = 1.0f / (1.0f + __expf(-(v.w + a.w)));
    ((float4*)out)[i] = v;
}

// ---- fallback (fp32 atomic path) if ws is too small ----
__global__ __launch_bounds__(256) void distmult_atomic(
    const float* __restrict__ h_drug, const float* __restrict__ h_disease,
    const float* __restrict__ W,
    const int* __restrict__ drug_src, const int* __restrict__ dis_dst,
    const int* __restrict__ dis_src, const int* __restrict__ drug_dst,
    float* __restrict__ out)
{
    const int b = blockIdx.x;
    const int slot = b & 7, chunk = slot >> 1, half = slot & 1;
    const int j = b >> 3;
    const int ro = j / 625, batch = j % 625;
    const int eg = threadIdx.x >> 3, lane = threadIdx.x & 7;

    const float* tabA; const float* tabB;
    const int* idxA; const int* idxB;
    if (ro < NREL) {
        tabA = h_drug;    tabB = h_disease;
        idxA = drug_src + (size_t)ro * EDGES;
        idxB = dis_dst  + (size_t)ro * EDGES;
    } else {
        tabA = h_disease; tabB = h_drug;
        idxA = dis_src  + (size_t)(ro - NREL) * EDGES;
        idxB = drug_dst + (size_t)(ro - NREL) * EDGES;
    }
    const int off = chunk * 32;
    const float4 w4 = ((const float4*)(W + (size_t)ro * DIM + off))[lane];

    #pragma unroll
    for (int p = 0; p < 5; ++p) {
        const int e = batch * 320 + p * 64 + half * 32 + eg;
        const int ia = __builtin_nontemporal_load(idxA + e);
        const int ib = __builtin_nontemporal_load(idxB + e);
        const float4 a4 = ((const float4*)(tabA + (size_t)ia * DIM + off))[lane];
        const float4 b4 = ((const float4*)(tabB + (size_t)ib * DIM + off))[lane];
        float s = a4.x * w4.x * b4.x + a4.y * w4.y * b4.y
                + a4.z * w4.z * b4.z + a4.w * w4.w * b4.w;
        s += __shfl_xor(s, 4, 64);
        s += __shfl_xor(s, 2, 64);
        s += __shfl_xor(s, 1, 64);
        if (lane == 0) atomicAdd(&out[(size_t)ro * EDGES + e], s);
    }
}

__global__ __launch_bounds__(256) void sigmoid_inplace(float* __restrict__ out)
{
    const int i = blockIdx.x * 256 + threadIdx.x;
    if (i >= (6 * EDGES) / 4) return;
    float4 v = ((float4*)out)[i];
    v.x = 1.0f / (1.0f + __expf(-v.x));
    v.y = 1.0f / (1.0f + __expf(-v.y));
    v.z = 1.0f / (1.0f + __expf(-v.z));
    v.w = 1.0f / (1.0f + __expf(-v.w));
    ((float4*)out)[i] = v;
}

extern "C" void kernel_launch(void* const* d_in, const int* in_sizes, int n_in,
                              void* d_out, int out_size, void* d_ws, size_t ws_size,
                              hipStream_t stream) {
    const float* h_drug    = (const float*)d_in[0];
    const float* h_disease = (const float*)d_in[1];
    const float* W         = (const float*)d_in[2];
    const int*   drug_src  = (const int*)d_in[3];
    const int*   dis_dst   = (const int*)d_in[4];
    const int*   dis_src   = (const int*)d_in[5];
    const int*   drug_dst  = (const int*)d_in[6];
    float*       out       = (float*)d_out;

    const int n4 = (6 * EDGES) / 4;                       // 300000
    const size_t tab_bytes = (size_t)TOT_ELEMS * 2;       // 6,656,000
    const size_t ws_need   = tab_bytes + (size_t)6 * EDGES * sizeof(float); // 11.46 MB

    if (ws_size >= ws_need) {
        _Float16* tabs  = (_Float16*)d_ws;
        float*    part1 = (float*)((char*)d_ws + tab_bytes);

        convert_fp16<<<(TOT_ELEMS / 8 + 255) / 256, 256, 0, stream>>>(
            h_drug, h_disease, tabs);
        distmult_fp16<<<VBLOCKS, 256, 0, stream>>>(
            tabs, W, drug_src, dis_dst, dis_src, drug_dst, out, part1);
        reduce_sigmoid<<<(n4 + 255) / 256, 256, 0, stream>>>(part1, out);
    } else {
        (void)hipMemsetAsync(out, 0, (size_t)6 * EDGES * sizeof(float), stream);
        distmult_atomic<<<8 * 6 * 625, 256, 0, stream>>>(
            h_drug, h_disease, W, drug_src, dis_dst, dis_src, drug_dst, out);
        sigmoid_inplace<<<(n4 + 255) / 256, 256, 0, stream>>>(out);
    }
}